// Round 2
// 372.055 us; speedup vs baseline: 1.0554x; 1.0554x over previous
//
#include <hip/hip_runtime.h>
#include <hip/hip_bf16.h>
#include <stdint.h>

// Problem dims
#define DMODEL 1024
#define DHID   1024
#define NBATCH 8
#define LSEQ   2048
#define MROWS  (NBATCH * LSEQ)   // 16384
#define KCAT   2048              // [h | x] concat K
#define CH     32                // scan chunk length
#define NCH    64                // LSEQ / CH
#define BH     (NBATCH * DHID)   // 8192
#define CPT    4                 // channels per scan thread

typedef __attribute__((ext_vector_type(8))) short  short8;
typedef __attribute__((ext_vector_type(4))) short  s16x4;
typedef __attribute__((ext_vector_type(8))) __bf16 bf16x8;
typedef __attribute__((ext_vector_type(4))) float  f32x4;

__device__ __forceinline__ unsigned short f2bf(float f) {
  union { float f; unsigned int u; } v; v.f = f;
  unsigned int u = v.u;
  u += 0x7fffu + ((u >> 16) & 1u);   // round-to-nearest-even
  return (unsigned short)(u >> 16);
}

__device__ __forceinline__ float bf2f(unsigned short s) {
  union { unsigned int u; float f; } v; v.u = ((unsigned int)s) << 16;
  return v.f;
}

__device__ __forceinline__ float softplus_f(float x) {
  return fmaxf(x, 0.f) + log1pf(expf(-fabsf(x)));   // == jax.nn.softplus
}

__device__ __forceinline__ short8 pack8(float4 a, float4 b) {
  short8 o;
  o[0] = (short)f2bf(a.x); o[1] = (short)f2bf(a.y);
  o[2] = (short)f2bf(a.z); o[3] = (short)f2bf(a.w);
  o[4] = (short)f2bf(b.x); o[5] = (short)f2bf(b.y);
  o[6] = (short)f2bf(b.z); o[7] = (short)f2bf(b.w);
  return o;
}

// ---- one cast kernel: x -> A2[:,1024:], W1=[dw;Bw], W2=[Cw|Dw] -----------
__global__ __launch_bounds__(256)
void cast_all_kernel(const float* __restrict__ x,
                     const float* __restrict__ dw, const float* __restrict__ Bw,
                     const float* __restrict__ Cw, const float* __restrict__ Dw,
                     unsigned short* __restrict__ A2,
                     unsigned short* __restrict__ W1, unsigned short* __restrict__ W2) {
  const size_t MX = (size_t)MROWS * 1024;       // 16M: x
  const size_t M1 = (size_t)1024 * 1024;        // 1M
  size_t i8 = ((size_t)blockIdx.x * 256 + threadIdx.x) * 8;
  if (i8 < MX) {
    size_t row = i8 >> 10; int col = (int)(i8 & 1023);
    const float4* p = (const float4*)(x + i8);
    *(short8*)(A2 + row * (size_t)KCAT + 1024 + col) = pack8(p[0], p[1]);
  } else if (i8 < MX + 2 * M1) {                // W1 rows 0..1023=dw, 1024..2047=Bw
    size_t k = i8 - MX;
    const float* src = (k < M1) ? (dw + k) : (Bw + k - M1);
    const float4* p = (const float4*)src;
    *(short8*)(W1 + k) = pack8(p[0], p[1]);
  } else {                                      // W2 row d: [Cw[d,:] | Dw[d,:]]
    size_t k = i8 - MX - 2 * M1;
    size_t d = k >> 11; int c = (int)(k & 2047);
    const float* src = (c < 1024) ? (Cw + d * 1024 + c) : (Dw + d * 1024 + (c - 1024));
    const float4* p = (const float4*)src;
    *(short8*)(W2 + k) = pack8(p[0], p[1]);
  }
}

// ---- GEMM: C[M,N] = A[M,K] @ B[N,K]^T ------------------------------------
// 256x256 tile, 8 waves (2M x 4N), BK=32, 4-deep LDS ring (4 x 32 KiB),
// counted vmcnt(8) pipeline (tiles t+2,t+3 in flight across barriers).
// LDS per K-tile buffer: A then B, each fragment-major:
//   element A[row=f*16+l16][col=q*8+j] at short-offset f*512 + q*128 + l16*8 + j
// so ds_read_b128 per fragment is base + lane*16B -> conflict-free, and
// global_load_lds's linear dest (uniform base + lane*16B) matches it when the
// GLOBAL source per lane is row f*16+(l&15), cols k0+(l>>4)*8 (m173 pattern).

__device__ __forceinline__ void stage_frag32(const unsigned short* __restrict__ gbase,
                                             int ld, int k0,
                                             unsigned short* sbase,
                                             int wave, int quad, int l16) {
#pragma unroll
  for (int s = 0; s < 2; ++s) {
    int f = s * 8 + wave;                                   // wave-uniform frag id
    const unsigned short* g = gbase + (size_t)(f * 16 + l16) * ld + k0 + quad * 8;
    unsigned short* sd = sbase + (size_t)(s * 512 + wave * 64) * 8;  // uniform base
    __builtin_amdgcn_global_load_lds(
        (const __attribute__((address_space(1))) unsigned int*)g,
        (__attribute__((address_space(3))) unsigned int*)sd, 16, 0, 0);
  }
}

// mode 0: f32 out, += bias0[n]+bias1[n];  mode 1: bf16 out, no bias
__global__ __launch_bounds__(512, 2)
void gemm256(const unsigned short* __restrict__ A, int lda,
             const unsigned short* __restrict__ B, int ldb,
             void* __restrict__ Cp, int ldc, int K, int mode,
             const float* __restrict__ bias0, const float* __restrict__ bias1) {
  __shared__ __align__(16) unsigned short smem[4 * 16384];   // 128 KiB: 4 bufs x (A 16K + B 16K bytes)
  const int tid  = threadIdx.x;
  const int lane = tid & 63;
  const int wave = tid >> 6;         // 0..7
  const int wr   = wave >> 2;        // 0..1  (M half of tile)
  const int wc   = wave & 3;         // 0..3  (N quarter of tile)
  const int quad = lane >> 4, l16 = lane & 15;

  // XCD-aware swizzle: each XCD (bid%8) owns a contiguous M-band, N-fastest.
  const int Nt = gridDim.x, Mt = gridDim.y;
  int bid  = blockIdx.y * Nt + blockIdx.x;
  int xcd  = bid & 7;
  int slot = bid >> 3;
  int lm = slot / Nt;
  int ln = slot - lm * Nt;
  const int m0 = (xcd * (Mt >> 3) + lm) * 256;
  const int n0 = ln * 256;

  const unsigned short* Ab = A + (size_t)m0 * lda;
  const unsigned short* Bb = B + (size_t)n0 * ldb;

  const int nt = K >> 5;             // K-tiles of 32 (nt >= 4 for our shapes)

  f32x4 acc[8][4] = {};

  // ---- prologue: issue tiles 0,1,2 (12 loads/thread); tile0 must land ----
#pragma unroll
  for (int t = 0; t < 3; ++t) {
    unsigned short* buf = smem + t * 16384;
    stage_frag32(Ab, lda, t * 32, buf, wave, quad, l16);
    stage_frag32(Bb, ldb, t * 32, buf + 8192, wave, quad, l16);
  }
  asm volatile("s_waitcnt vmcnt(8)" ::: "memory");   // tile 0 landed; tiles 1,2 in flight
  __builtin_amdgcn_s_barrier();
  __builtin_amdgcn_sched_barrier(0);

  // ---- main loop: 2 phases per K-tile, 16 MFMA per phase -----------------
  for (int t = 0; t < nt; ++t) {
    const unsigned short* As = smem + (t & 3) * 16384;
    const unsigned short* Bs = As + 8192;
    unsigned short* nbuf = smem + ((t + 3) & 3) * 16384;
    const bool pf = (t + 3) < nt;
    const int kpf = (t + 3) * 32;
#pragma unroll
    for (int ph = 0; ph < 2; ++ph) {
      short8 af[4], bfr[4];
#pragma unroll
      for (int i = 0; i < 4; ++i)
        af[i] = *(const short8*)(As + (size_t)(wr * 8 + ph * 4 + i) * 512 + lane * 8);
#pragma unroll
      for (int j = 0; j < 4; ++j)
        bfr[j] = *(const short8*)(Bs + (size_t)(wc * 4 + j) * 512 + lane * 8);
      if (pf) {
        if (ph == 0) stage_frag32(Ab, lda, kpf, nbuf, wave, quad, l16);
        else         stage_frag32(Bb, ldb, kpf, nbuf + 8192, wave, quad, l16);
      }
      __builtin_amdgcn_s_barrier();
      __builtin_amdgcn_sched_barrier(0);
      __builtin_amdgcn_s_setprio(1);
#pragma unroll
      for (int i = 0; i < 4; ++i)
#pragma unroll
        for (int j = 0; j < 4; ++j)
          acc[ph * 4 + i][j] = __builtin_amdgcn_mfma_f32_16x16x32_bf16(
              __builtin_bit_cast(bf16x8, af[i]),
              __builtin_bit_cast(bf16x8, bfr[j]), acc[ph * 4 + i][j], 0, 0, 0);
      __builtin_amdgcn_s_setprio(0);
      if (ph == 1) {
        // end-of-tile: ensure tile t+1 landed; keep tiles t+2,t+3 in flight
        if (t + 3 < nt)      { asm volatile("s_waitcnt vmcnt(8)" ::: "memory"); }
        else if (t + 2 < nt) { asm volatile("s_waitcnt vmcnt(4)" ::: "memory"); }
        else if (t + 1 < nt) { asm volatile("s_waitcnt vmcnt(0)" ::: "memory"); }
      }
      __builtin_amdgcn_s_barrier();
      __builtin_amdgcn_sched_barrier(0);
    }
  }

  // ---- epilogue: C-write (verified mapping: col=lane&15, row=quad*4+r) ---
  if (mode == 0) {
    float* C = (float*)Cp;
#pragma unroll
    for (int mi = 0; mi < 8; ++mi)
#pragma unroll
      for (int j = 0; j < 4; ++j) {
        int n  = n0 + wc * 64 + j * 16 + l16;
        int mb = m0 + wr * 128 + mi * 16 + quad * 4;
        float badd = bias0[n] + bias1[n];
#pragma unroll
        for (int r = 0; r < 4; ++r)
          C[(size_t)(mb + r) * ldc + n] = acc[mi][j][r] + badd;
      }
  } else {
    unsigned short* C16 = (unsigned short*)Cp;
#pragma unroll
    for (int mi = 0; mi < 8; ++mi)
#pragma unroll
      for (int j = 0; j < 4; ++j) {
        int n  = n0 + wc * 64 + j * 16 + l16;
        int mb = m0 + wr * 128 + mi * 16 + quad * 4;
#pragma unroll
        for (int r = 0; r < 4; ++r)
          C16[(size_t)(mb + r) * ldc + n] = f2bf(acc[mi][j][r]);
      }
  }
}

// ---- scan pass A: pointwise (in-place) + per-chunk carries --------------
__global__ __launch_bounds__(256)
void scan_carry_kernel(unsigned short* __restrict__ G1,
                       const float* __restrict__ Av, const float* __restrict__ Bbv,
                       const float* __restrict__ dbv, float2* __restrict__ carr) {
  int t = blockIdx.x * 256 + threadIdx.x;      // 131072 = 8 * 64 * 256
  int ho = t & 255, chunk = (t >> 8) & (NCH - 1), b = t >> 14;
  int h0 = ho << 2;
  float4 A0 = *(const float4*)(Av + h0);
  float4 B0 = *(const float4*)(Bbv + h0);
  float4 D0 = *(const float4*)(dbv + h0);
  float Ah[4]  = {A0.x, A0.y, A0.z, A0.w};
  float Bbh[4] = {B0.x, B0.y, B0.z, B0.w};
  float dbh[4] = {D0.x, D0.y, D0.z, D0.w};
  unsigned short* base = G1 + ((size_t)(b * LSEQ + chunk * CH)) * KCAT + h0;
  float hs[4] = {}, sd[4] = {};
  s16x4 dp = *(const s16x4*)(base);
  s16x4 bp = *(const s16x4*)(base + 1024);
#pragma unroll 4
  for (int l = 0; l < CH; ++l) {
    s16x4 dpn = dp, bpn = bp;
    if (l + 1 < CH) {                           // prefetch next step
      dpn = *(const s16x4*)(base + (size_t)(l + 1) * KCAT);
      bpn = *(const s16x4*)(base + (size_t)(l + 1) * KCAT + 1024);
    }
    s16x4 dq, bq;
#pragma unroll
    for (int j = 0; j < 4; ++j) {
      float d = softplus_f(bf2f((unsigned short)dp[j]) + dbh[j]);
      unsigned short dr = f2bf(d);
      float drf = bf2f(dr);
      float bb = drf * (bf2f((unsigned short)bp[j]) + Bbh[j]);
      unsigned short br = f2bf(bb);
      sd[j] += drf;
      float a = __expf(drf * Ah[j]);
      hs[j] = fmaf(a, hs[j], bf2f(br));
      dq[j] = (short)dr; bq[j] = (short)br;
    }
    *(s16x4*)(base + (size_t)l * KCAT) = dq;
    *(s16x4*)(base + (size_t)l * KCAT + 1024) = bq;
    dp = dpn; bp = bpn;
  }
  float2* cb = carr + (size_t)chunk * BH + b * 1024 + h0;
#pragma unroll
  for (int j = 0; j < 4; ++j)
    cb[j] = make_float2(__expf(Ah[j] * sd[j]), hs[j]);
}

// ---- scan pass B: compose carries (lane-contiguous) ---------------------
__global__ __launch_bounds__(256)
void scan_comb_kernel(const float2* __restrict__ carr, float* __restrict__ Hc) {
  int t = blockIdx.x * 256 + threadIdx.x;   // 8192 = B*DH
  float H = 0.f;
#pragma unroll
  for (int c = 0; c < NCH; ++c) {
    float2 ah = carr[(size_t)c * BH + t];
    Hc[(size_t)c * BH + t] = H;              // carry-in for chunk c
    H = fmaf(ah.x, H, ah.y);
  }
}

// ---- scan pass C: recompute with carry, emit h bf16 into A2[:,0:1024] ---
__global__ __launch_bounds__(256)
void scan_final_kernel(const unsigned short* __restrict__ G1,
                       const float* __restrict__ Av, const float* __restrict__ Hc,
                       unsigned short* __restrict__ A2) {
  int t = blockIdx.x * 256 + threadIdx.x;      // 131072
  int ho = t & 255, chunk = (t >> 8) & (NCH - 1), b = t >> 14;
  int h0 = ho << 2;
  float4 A0 = *(const float4*)(Av + h0);
  float Ah[4] = {A0.x, A0.y, A0.z, A0.w};
  const unsigned short* base = G1 + ((size_t)(b * LSEQ + chunk * CH)) * KCAT + h0;
  unsigned short* obase = A2 + ((size_t)(b * LSEQ + chunk * CH)) * KCAT + h0;
  const float* hb = Hc + (size_t)chunk * BH + b * 1024 + h0;
  float hs[4];
#pragma unroll
  for (int j = 0; j < 4; ++j) hs[j] = hb[j];
  s16x4 dp = *(const s16x4*)(base);
  s16x4 bp = *(const s16x4*)(base + 1024);
#pragma unroll 4
  for (int l = 0; l < CH; ++l) {
    s16x4 dpn = dp, bpn = bp;
    if (l + 1 < CH) {                           // prefetch next step
      dpn = *(const s16x4*)(base + (size_t)(l + 1) * KCAT);
      bpn = *(const s16x4*)(base + (size_t)(l + 1) * KCAT + 1024);
    }
    s16x4 o;
#pragma unroll
    for (int j = 0; j < 4; ++j) {
      float d = bf2f((unsigned short)dp[j]);
      float a = __expf(d * Ah[j]);
      hs[j] = fmaf(a, hs[j], bf2f((unsigned short)bp[j]));
      o[j] = (short)f2bf(hs[j]);
    }
    *(s16x4*)(obase + (size_t)l * KCAT) = o;
    dp = dpn; bp = bpn;
  }
}

extern "C" void kernel_launch(void* const* d_in, const int* in_sizes, int n_in,
                              void* d_out, int out_size, void* d_ws, size_t ws_size,
                              hipStream_t stream) {
  const float* x  = (const float*)d_in[0];
  const float* Av = (const float*)d_in[1];
  const float* Bw = (const float*)d_in[2];
  const float* Bb = (const float*)d_in[3];
  const float* Cw = (const float*)d_in[4];
  const float* Cb = (const float*)d_in[5];
  const float* Dw = (const float*)d_in[6];
  const float* Db = (const float*)d_in[7];
  const float* dw = (const float*)d_in[8];
  const float* db = (const float*)d_in[9];
  float* out = (float*)d_out;

  // Workspace (138 MiB, same as proven rounds):
  //   A2 [16384,2048] bf16 = 64 MiB ([h | x])
  //   G1 [16384,2048] bf16 = 64 MiB ([dpre|bpre] -> in-place [d|bb])
  //   W1 [2048,1024]  bf16 =  4 MiB ([dw;Bw]; reused as carr after GEMM1)
  //   W2 [1024,2048]  bf16 =  4 MiB ([Cw|Dw])
  //   Hc [64,8192]    f32  =  2 MiB
  const size_t sz_big = (size_t)MROWS * KCAT * 2;
  const size_t sz_w   = (size_t)2048 * 1024 * 2;
  const size_t sz_hc  = (size_t)NCH * BH * 4;
  const size_t need = 2 * sz_big + 2 * sz_w + sz_hc;
  if (ws_size < need) return;

  char* w = (char*)d_ws;
  unsigned short* A2 = (unsigned short*)w; w += sz_big;
  unsigned short* G1 = (unsigned short*)w; w += sz_big;
  unsigned short* W1 = (unsigned short*)w; w += sz_w;
  unsigned short* W2 = (unsigned short*)w; w += sz_w;
  float* Hc = (float*)w;                   w += sz_hc;
  float2* carr = (float2*)W1;  // W1 dead after GEMM1; carr = NCH*BH*8 = 4 MiB exactly

  // cast everything (x, W1, W2) in one launch
  const size_t cast_elems = (size_t)MROWS * 1024 + 2 * (size_t)2048 * 1024;
  cast_all_kernel<<<(int)(cast_elems / (256 * 8)), 256, 0, stream>>>(
      x, dw, Bw, Cw, Dw, A2, W1, W2);

  // GEMM1: G1 = x @ [dw;Bw]^T -> [dpre | bpre]  (M=16384,N=2048,K=1024), bf16
  dim3 g1(KCAT / 256, MROWS / 256);        // (8, 64)
  gemm256<<<g1, 512, 0, stream>>>(A2 + 1024, KCAT, W1, 1024, G1, KCAT, 1024, 1,
                                  nullptr, nullptr);

  // chunked scan: pointwise (softplus once, in-place) + carries, compose, final
  scan_carry_kernel<<<(NBATCH * NCH * (DHID / CPT)) / 256, 256, 0, stream>>>(
      G1, Av, Bb, db, carr);
  scan_comb_kernel<<<BH / 256, 256, 0, stream>>>(carr, Hc);
  scan_final_kernel<<<(NBATCH * NCH * (DHID / CPT)) / 256, 256, 0, stream>>>(
      G1, Av, Hc, A2);

  // GEMM2: out = [h | x] @ [Cw|Dw]^T + Cb + Db  (M=16384,N=1024,K=2048), f32
  dim3 g2(DMODEL / 256, MROWS / 256);      // (4, 64)
  gemm256<<<g2, 512, 0, stream>>>(A2, KCAT, W2, KCAT, out, DMODEL, KCAT, 0, Cb, Db);
}

// Round 3
// 371.457 us; speedup vs baseline: 1.0571x; 1.0016x over previous
//
#include <hip/hip_runtime.h>
#include <hip/hip_bf16.h>
#include <stdint.h>

// Problem dims
#define DMODEL 1024
#define DHID   1024
#define NBATCH 8
#define LSEQ   2048
#define MROWS  (NBATCH * LSEQ)   // 16384
#define KCAT   2048              // [h | x] concat K
#define CH     32                // scan chunk length
#define NCH    64                // LSEQ / CH
#define BH     (NBATCH * DHID)   // 8192
#define CPT    4                 // channels per scan thread

typedef __attribute__((ext_vector_type(8))) short  short8;
typedef __attribute__((ext_vector_type(4))) short  s16x4;
typedef __attribute__((ext_vector_type(8))) __bf16 bf16x8;
typedef __attribute__((ext_vector_type(4))) float  f32x4;

__device__ __forceinline__ unsigned short f2bf(float f) {
  union { float f; unsigned int u; } v; v.f = f;
  unsigned int u = v.u;
  u += 0x7fffu + ((u >> 16) & 1u);   // round-to-nearest-even
  return (unsigned short)(u >> 16);
}

__device__ __forceinline__ float bf2f(unsigned short s) {
  union { unsigned int u; float f; } v; v.u = ((unsigned int)s) << 16;
  return v.f;
}

__device__ __forceinline__ float softplus_f(float x) {
  return fmaxf(x, 0.f) + log1pf(expf(-fabsf(x)));   // == jax.nn.softplus
}

__device__ __forceinline__ short8 pack8(float4 a, float4 b) {
  short8 o;
  o[0] = (short)f2bf(a.x); o[1] = (short)f2bf(a.y);
  o[2] = (short)f2bf(a.z); o[3] = (short)f2bf(a.w);
  o[4] = (short)f2bf(b.x); o[5] = (short)f2bf(b.y);
  o[6] = (short)f2bf(b.z); o[7] = (short)f2bf(b.w);
  return o;
}

// ---- one cast kernel: x -> A2[:,1024:], W1=[dw;Bw], W2=[Cw|Dw] -----------
__global__ __launch_bounds__(256)
void cast_all_kernel(const float* __restrict__ x,
                     const float* __restrict__ dw, const float* __restrict__ Bw,
                     const float* __restrict__ Cw, const float* __restrict__ Dw,
                     unsigned short* __restrict__ A2,
                     unsigned short* __restrict__ W1, unsigned short* __restrict__ W2) {
  const size_t MX = (size_t)MROWS * 1024;       // 16M: x
  const size_t M1 = (size_t)1024 * 1024;        // 1M
  size_t i8 = ((size_t)blockIdx.x * 256 + threadIdx.x) * 8;
  if (i8 < MX) {
    size_t row = i8 >> 10; int col = (int)(i8 & 1023);
    const float4* p = (const float4*)(x + i8);
    *(short8*)(A2 + row * (size_t)KCAT + 1024 + col) = pack8(p[0], p[1]);
  } else if (i8 < MX + 2 * M1) {                // W1 rows 0..1023=dw, 1024..2047=Bw
    size_t k = i8 - MX;
    const float* src = (k < M1) ? (dw + k) : (Bw + k - M1);
    const float4* p = (const float4*)src;
    *(short8*)(W1 + k) = pack8(p[0], p[1]);
  } else {                                      // W2 row d: [Cw[d,:] | Dw[d,:]]
    size_t k = i8 - MX - 2 * M1;
    size_t d = k >> 11; int c = (int)(k & 2047);
    const float* src = (c < 1024) ? (Cw + d * 1024 + c) : (Dw + d * 1024 + (c - 1024));
    const float4* p = (const float4*)src;
    *(short8*)(W2 + k) = pack8(p[0], p[1]);
  }
}

// ---- GEMM: C[M,N] = A[M,K] @ B[N,K]^T ------------------------------------
// 256x256 tile, 8 waves (2M x 4N), BK=32, 4-deep LDS ring (4 x 32 KiB),
// counted vmcnt(8) pipeline, ONE barrier per K-tile, software-pipelined:
//   A: issue stage(t+3) + ds_read af1(t)     (overlapped by B)
//   B: MFMA ph0 (af0(t) x bfr(t))
//   C: lgkmcnt(0) [WAR safety] + counted vmcnt + s_barrier
//   D: issue ds_read bfr(t+1), af0(t+1)      (overlapped by E)
//   E: MFMA ph1 (af1(t) x bfr(t))
// Hazards: all reads of a buffer complete before each wave's barrier at its
// last-use tile; next write to that buffer is issued only after that barrier.
// LDS per K-tile buffer: A then B, fragment-major:
//   element A[row=f*16+l16][col=q*8+j] at short-offset f*512 + q*128 + l16*8 + j
// -> every ds_read_b128 is base + lane*16B (conflict-free); global_load_lds's
// linear dest matches it with the pre-permuted global source (m173 pattern).

__device__ __forceinline__ void stage_frag32(const unsigned short* __restrict__ gbase,
                                             int ld, int k0,
                                             unsigned short* sbase,
                                             int wave, int quad, int l16) {
#pragma unroll
  for (int s = 0; s < 2; ++s) {
    int f = s * 8 + wave;                                   // wave-uniform frag id
    const unsigned short* g = gbase + (size_t)(f * 16 + l16) * ld + k0 + quad * 8;
    unsigned short* sd = sbase + (size_t)(s * 512 + wave * 64) * 8;  // uniform base
    __builtin_amdgcn_global_load_lds(
        (const __attribute__((address_space(1))) unsigned int*)g,
        (__attribute__((address_space(3))) unsigned int*)sd, 16, 0, 0);
  }
}

#define TILE_BODY(T, BCUR, BNXT)                                              \
  {                                                                           \
    const int t_ = (T);                                                       \
    const unsigned short* As_ = smem + (t_ & 3) * 16384;                      \
    if (t_ + 3 < nt) {                                                        \
      unsigned short* nb_ = smem + ((t_ + 3) & 3) * 16384;                    \
      stage_frag32(Ab, lda, (t_ + 3) * 32, nb_, wave, quad, l16);             \
      stage_frag32(Bb, ldb, (t_ + 3) * 32, nb_ + 8192, wave, quad, l16);      \
    }                                                                         \
    _Pragma("unroll")                                                         \
    for (int i = 0; i < 4; ++i)                                               \
      af1[i] = *(const short8*)(As_ + (size_t)(wr * 8 + 4 + i) * 512 + lane * 8); \
    __builtin_amdgcn_sched_barrier(0);                                        \
    __builtin_amdgcn_s_setprio(1);                                            \
    _Pragma("unroll")                                                         \
    for (int i = 0; i < 4; ++i) {                                             \
      _Pragma("unroll")                                                       \
      for (int j = 0; j < 4; ++j)                                             \
        acc[i][j] = __builtin_amdgcn_mfma_f32_16x16x32_bf16(                  \
            __builtin_bit_cast(bf16x8, af0[i]),                               \
            __builtin_bit_cast(bf16x8, BCUR[j]), acc[i][j], 0, 0, 0);         \
    }                                                                         \
    __builtin_amdgcn_s_setprio(0);                                            \
    __builtin_amdgcn_sched_barrier(0);                                        \
    asm volatile("s_waitcnt lgkmcnt(0)" ::: "memory");                        \
    if (t_ + 3 < nt)      { asm volatile("s_waitcnt vmcnt(8)" ::: "memory"); }\
    else if (t_ + 2 < nt) { asm volatile("s_waitcnt vmcnt(4)" ::: "memory"); }\
    else if (t_ + 1 < nt) { asm volatile("s_waitcnt vmcnt(0)" ::: "memory"); }\
    __builtin_amdgcn_s_barrier();                                             \
    __builtin_amdgcn_sched_barrier(0);                                        \
    if (t_ + 1 < nt) {                                                        \
      const unsigned short* An_ = smem + ((t_ + 1) & 3) * 16384;              \
      _Pragma("unroll")                                                       \
      for (int j = 0; j < 4; ++j)                                             \
        BNXT[j] = *(const short8*)(An_ + 8192 + (size_t)(wc * 4 + j) * 512 + lane * 8); \
      _Pragma("unroll")                                                       \
      for (int i = 0; i < 4; ++i)                                             \
        af0[i] = *(const short8*)(An_ + (size_t)(wr * 8 + i) * 512 + lane * 8); \
    }                                                                         \
    __builtin_amdgcn_sched_barrier(0);                                        \
    __builtin_amdgcn_s_setprio(1);                                            \
    _Pragma("unroll")                                                         \
    for (int i = 0; i < 4; ++i) {                                             \
      _Pragma("unroll")                                                       \
      for (int j = 0; j < 4; ++j)                                             \
        acc[4 + i][j] = __builtin_amdgcn_mfma_f32_16x16x32_bf16(              \
            __builtin_bit_cast(bf16x8, af1[i]),                               \
            __builtin_bit_cast(bf16x8, BCUR[j]), acc[4 + i][j], 0, 0, 0);     \
    }                                                                         \
    __builtin_amdgcn_s_setprio(0);                                            \
    __builtin_amdgcn_sched_barrier(0);                                        \
  }

// mode 0: f32 out, += bias0[n]+bias1[n];  mode 1: bf16 out, no bias
__global__ __launch_bounds__(512, 2)
void gemm256(const unsigned short* __restrict__ A, int lda,
             const unsigned short* __restrict__ B, int ldb,
             void* __restrict__ Cp, int ldc, int K, int mode,
             const float* __restrict__ bias0, const float* __restrict__ bias1) {
  __shared__ __align__(16) unsigned short smem[4 * 16384];   // 128 KiB ring
  const int tid  = threadIdx.x;
  const int lane = tid & 63;
  const int wave = tid >> 6;         // 0..7
  const int wr   = wave >> 2;        // 0..1  (M half of tile)
  const int wc   = wave & 3;         // 0..3  (N quarter of tile)
  const int quad = lane >> 4, l16 = lane & 15;

  // XCD-aware swizzle: each XCD (bid%8) owns a contiguous M-band, N-fastest.
  const int Nt = gridDim.x, Mt = gridDim.y;
  int bid  = blockIdx.y * Nt + blockIdx.x;
  int xcd  = bid & 7;
  int slot = bid >> 3;
  int lm = slot / Nt;
  int ln = slot - lm * Nt;
  const int m0 = (xcd * (Mt >> 3) + lm) * 256;
  const int n0 = ln * 256;

  const unsigned short* Ab = A + (size_t)m0 * lda;
  const unsigned short* Bb = B + (size_t)n0 * ldb;

  const int nt = K >> 5;             // K-tiles of 32; even and >= 4 here

  f32x4 acc[8][4] = {};
  short8 af0[4], af1[4], bfrE[4], bfrO[4];

  // ---- prologue: issue tiles 0,1,2; tile0 must land; preload its frags ---
#pragma unroll
  for (int t = 0; t < 3; ++t) {
    unsigned short* buf = smem + t * 16384;
    stage_frag32(Ab, lda, t * 32, buf, wave, quad, l16);
    stage_frag32(Bb, ldb, t * 32, buf + 8192, wave, quad, l16);
  }
  asm volatile("s_waitcnt vmcnt(8)" ::: "memory");   // tile 0 landed
  __builtin_amdgcn_s_barrier();
  __builtin_amdgcn_sched_barrier(0);
#pragma unroll
  for (int j = 0; j < 4; ++j)
    bfrE[j] = *(const short8*)(smem + 8192 + (size_t)(wc * 4 + j) * 512 + lane * 8);
#pragma unroll
  for (int i = 0; i < 4; ++i)
    af0[i] = *(const short8*)(smem + (size_t)(wr * 8 + i) * 512 + lane * 8);
  __builtin_amdgcn_sched_barrier(0);

  // ---- main loop: 2 tiles per iteration (bfr parity), 1 barrier/tile ----
  for (int t = 0; t < nt; t += 2) {
    TILE_BODY(t,     bfrE, bfrO)
    TILE_BODY(t + 1, bfrO, bfrE)
  }

  // ---- epilogue: C-write (verified mapping: col=lane&15, row=quad*4+r) ---
  if (mode == 0) {
    float* C = (float*)Cp;
#pragma unroll
    for (int mi = 0; mi < 8; ++mi)
#pragma unroll
      for (int j = 0; j < 4; ++j) {
        int n  = n0 + wc * 64 + j * 16 + l16;
        int mb = m0 + wr * 128 + mi * 16 + quad * 4;
        float badd = bias0[n] + bias1[n];
#pragma unroll
        for (int r = 0; r < 4; ++r)
          C[(size_t)(mb + r) * ldc + n] = acc[mi][j][r] + badd;
      }
  } else {
    unsigned short* C16 = (unsigned short*)Cp;
#pragma unroll
    for (int mi = 0; mi < 8; ++mi)
#pragma unroll
      for (int j = 0; j < 4; ++j) {
        int n  = n0 + wc * 64 + j * 16 + l16;
        int mb = m0 + wr * 128 + mi * 16 + quad * 4;
#pragma unroll
        for (int r = 0; r < 4; ++r)
          C16[(size_t)(mb + r) * ldc + n] = f2bf(acc[mi][j][r]);
      }
  }
}

// ---- scan pass A: pointwise (in-place) + per-chunk carries --------------
__global__ __launch_bounds__(256)
void scan_carry_kernel(unsigned short* __restrict__ G1,
                       const float* __restrict__ Av, const float* __restrict__ Bbv,
                       const float* __restrict__ dbv, float2* __restrict__ carr) {
  int t = blockIdx.x * 256 + threadIdx.x;      // 131072 = 8 * 64 * 256
  int ho = t & 255, chunk = (t >> 8) & (NCH - 1), b = t >> 14;
  int h0 = ho << 2;
  float4 A0 = *(const float4*)(Av + h0);
  float4 B0 = *(const float4*)(Bbv + h0);
  float4 D0 = *(const float4*)(dbv + h0);
  float Ah[4]  = {A0.x, A0.y, A0.z, A0.w};
  float Bbh[4] = {B0.x, B0.y, B0.z, B0.w};
  float dbh[4] = {D0.x, D0.y, D0.z, D0.w};
  unsigned short* base = G1 + ((size_t)(b * LSEQ + chunk * CH)) * KCAT + h0;
  float hs[4] = {}, sd[4] = {};
  s16x4 dp = *(const s16x4*)(base);
  s16x4 bp = *(const s16x4*)(base + 1024);
#pragma unroll 4
  for (int l = 0; l < CH; ++l) {
    s16x4 dpn = dp, bpn = bp;
    if (l + 1 < CH) {                           // prefetch next step
      dpn = *(const s16x4*)(base + (size_t)(l + 1) * KCAT);
      bpn = *(const s16x4*)(base + (size_t)(l + 1) * KCAT + 1024);
    }
    s16x4 dq, bq;
#pragma unroll
    for (int j = 0; j < 4; ++j) {
      float d = softplus_f(bf2f((unsigned short)dp[j]) + dbh[j]);
      unsigned short dr = f2bf(d);
      float drf = bf2f(dr);
      float bb = drf * (bf2f((unsigned short)bp[j]) + Bbh[j]);
      unsigned short br = f2bf(bb);
      sd[j] += drf;
      float a = __expf(drf * Ah[j]);
      hs[j] = fmaf(a, hs[j], bf2f(br));
      dq[j] = (short)dr; bq[j] = (short)br;
    }
    *(s16x4*)(base + (size_t)l * KCAT) = dq;
    *(s16x4*)(base + (size_t)l * KCAT + 1024) = bq;
    dp = dpn; bp = bpn;
  }
  float2* cb = carr + (size_t)chunk * BH + b * 1024 + h0;
#pragma unroll
  for (int j = 0; j < 4; ++j)
    cb[j] = make_float2(__expf(Ah[j] * sd[j]), hs[j]);
}

// ---- scan pass B: compose carries (lane-contiguous) ---------------------
__global__ __launch_bounds__(256)
void scan_comb_kernel(const float2* __restrict__ carr, float* __restrict__ Hc) {
  int t = blockIdx.x * 256 + threadIdx.x;   // 8192 = B*DH
  float H = 0.f;
#pragma unroll
  for (int c = 0; c < NCH; ++c) {
    float2 ah = carr[(size_t)c * BH + t];
    Hc[(size_t)c * BH + t] = H;              // carry-in for chunk c
    H = fmaf(ah.x, H, ah.y);
  }
}

// ---- scan pass C: recompute with carry, emit h bf16 into A2[:,0:1024] ---
__global__ __launch_bounds__(256)
void scan_final_kernel(const unsigned short* __restrict__ G1,
                       const float* __restrict__ Av, const float* __restrict__ Hc,
                       unsigned short* __restrict__ A2) {
  int t = blockIdx.x * 256 + threadIdx.x;      // 131072
  int ho = t & 255, chunk = (t >> 8) & (NCH - 1), b = t >> 14;
  int h0 = ho << 2;
  float4 A0 = *(const float4*)(Av + h0);
  float Ah[4] = {A0.x, A0.y, A0.z, A0.w};
  const unsigned short* base = G1 + ((size_t)(b * LSEQ + chunk * CH)) * KCAT + h0;
  unsigned short* obase = A2 + ((size_t)(b * LSEQ + chunk * CH)) * KCAT + h0;
  const float* hb = Hc + (size_t)chunk * BH + b * 1024 + h0;
  float hs[4];
#pragma unroll
  for (int j = 0; j < 4; ++j) hs[j] = hb[j];
  s16x4 dp = *(const s16x4*)(base);
  s16x4 bp = *(const s16x4*)(base + 1024);
#pragma unroll 4
  for (int l = 0; l < CH; ++l) {
    s16x4 dpn = dp, bpn = bp;
    if (l + 1 < CH) {                           // prefetch next step
      dpn = *(const s16x4*)(base + (size_t)(l + 1) * KCAT);
      bpn = *(const s16x4*)(base + (size_t)(l + 1) * KCAT + 1024);
    }
    s16x4 o;
#pragma unroll
    for (int j = 0; j < 4; ++j) {
      float d = bf2f((unsigned short)dp[j]);
      float a = __expf(d * Ah[j]);
      hs[j] = fmaf(a, hs[j], bf2f((unsigned short)bp[j]));
      o[j] = (short)f2bf(hs[j]);
    }
    *(s16x4*)(obase + (size_t)l * KCAT) = o;
    dp = dpn; bp = bpn;
  }
}

extern "C" void kernel_launch(void* const* d_in, const int* in_sizes, int n_in,
                              void* d_out, int out_size, void* d_ws, size_t ws_size,
                              hipStream_t stream) {
  const float* x  = (const float*)d_in[0];
  const float* Av = (const float*)d_in[1];
  const float* Bw = (const float*)d_in[2];
  const float* Bb = (const float*)d_in[3];
  const float* Cw = (const float*)d_in[4];
  const float* Cb = (const float*)d_in[5];
  const float* Dw = (const float*)d_in[6];
  const float* Db = (const float*)d_in[7];
  const float* dw = (const float*)d_in[8];
  const float* db = (const float*)d_in[9];
  float* out = (float*)d_out;

  // Workspace (138 MiB, same as proven rounds):
  //   A2 [16384,2048] bf16 = 64 MiB ([h | x])
  //   G1 [16384,2048] bf16 = 64 MiB ([dpre|bpre] -> in-place [d|bb])
  //   W1 [2048,1024]  bf16 =  4 MiB ([dw;Bw]; reused as carr after GEMM1)
  //   W2 [1024,2048]  bf16 =  4 MiB ([Cw|Dw])
  //   Hc [64,8192]    f32  =  2 MiB
  const size_t sz_big = (size_t)MROWS * KCAT * 2;
  const size_t sz_w   = (size_t)2048 * 1024 * 2;
  const size_t sz_hc  = (size_t)NCH * BH * 4;
  const size_t need = 2 * sz_big + 2 * sz_w + sz_hc;
  if (ws_size < need) return;

  char* w = (char*)d_ws;
  unsigned short* A2 = (unsigned short*)w; w += sz_big;
  unsigned short* G1 = (unsigned short*)w; w += sz_big;
  unsigned short* W1 = (unsigned short*)w; w += sz_w;
  unsigned short* W2 = (unsigned short*)w; w += sz_w;
  float* Hc = (float*)w;                   w += sz_hc;
  float2* carr = (float2*)W1;  // W1 dead after GEMM1; carr = NCH*BH*8 = 4 MiB exactly

  // cast everything (x, W1, W2) in one launch
  const size_t cast_elems = (size_t)MROWS * 1024 + 2 * (size_t)2048 * 1024;
  cast_all_kernel<<<(int)(cast_elems / (256 * 8)), 256, 0, stream>>>(
      x, dw, Bw, Cw, Dw, A2, W1, W2);

  // GEMM1: G1 = x @ [dw;Bw]^T -> [dpre | bpre]  (M=16384,N=2048,K=1024), bf16
  dim3 g1(KCAT / 256, MROWS / 256);        // (8, 64)
  gemm256<<<g1, 512, 0, stream>>>(A2 + 1024, KCAT, W1, 1024, G1, KCAT, 1024, 1,
                                  nullptr, nullptr);

  // chunked scan: pointwise (softplus once, in-place) + carries, compose, final
  scan_carry_kernel<<<(NBATCH * NCH * (DHID / CPT)) / 256, 256, 0, stream>>>(
      G1, Av, Bb, db, carr);
  scan_comb_kernel<<<BH / 256, 256, 0, stream>>>(carr, Hc);
  scan_final_kernel<<<(NBATCH * NCH * (DHID / CPT)) / 256, 256, 0, stream>>>(
      G1, Av, Hc, A2);

  // GEMM2: out = [h | x] @ [Cw|Dw]^T + Cb + Db  (M=16384,N=1024,K=2048), f32
  dim3 g2(DMODEL / 256, MROWS / 256);      // (4, 64)
  gemm256<<<g2, 512, 0, stream>>>(A2, KCAT, W2, KCAT, out, DMODEL, KCAT, 0, Cb, Db);
}